// Round 18
// baseline (456.876 us; speedup 1.0000x reference)
//
#include <hip/hip_runtime.h>
#include <hip/hip_bf16.h>
#include <math.h>

#define D_ 256
#define H_ 4
#define C_ 64

typedef __attribute__((ext_vector_type(8))) short short8;
typedef __attribute__((ext_vector_type(4))) float f32x4;

// ---------- helpers ----------
__device__ inline float lrelu(float v) { return v >= 0.f ? v : 0.2f * v; }

// bf16 bit helpers
__device__ inline unsigned short f2b(float f) {
    unsigned u = __float_as_uint(f);
    u = (u + 0x7FFFu + ((u >> 16) & 1u)) >> 16;   // round-to-nearest-even
    return (unsigned short)u;
}
__device__ inline float b2f(unsigned short u) {
    return __uint_as_float(((unsigned)u) << 16);
}

// ---------- W -> bf16 ----------
__global__ __launch_bounds__(256) void convert_w(
    const float* __restrict__ Wl, const float* __restrict__ Wr,
    unsigned short* __restrict__ Wb)
{
    int i4 = blockIdx.x * 256 + threadIdx.x;          // 0..32767 float4s
    float4 v = (i4 < 16384) ? ((const float4*)Wl)[i4]
                            : ((const float4*)Wr)[i4 - 16384];
    ushort4 u;
    u.x = f2b(v.x); u.y = f2b(v.y); u.z = f2b(v.z); u.w = f2b(v.w);
    ((ushort4*)Wb)[i4] = u;
}

// ---------- merged MFMA GEMM, ZERO-BARRIER: no LDS, fragments direct ----------
// With sel merged, each x row is consumed by one block (sibling wave's re-read
// is an L2 hit) and W (256 KB bf16) is L2-resident for all blocks -> LDS buys
// no reuse, only the vmcnt(0)+barrier drain (the structural stall, r17 halved
// it for -25us). Barrier-free lets each wave software-pipeline independently.
template <bool RB16>
__global__ __launch_bounds__(256, 2) void gemm_hist(
    const float* __restrict__ x, const unsigned short* __restrict__ Wb,
    const float* __restrict__ b_l, const float* __restrict__ b_r,
    const float* __restrict__ attn, const float* __restrict__ rel_l,
    const float* __restrict__ rel_r,
    unsigned short* __restrict__ lout, void* __restrict__ rout,
    float2* __restrict__ ej2, float* __restrict__ al, float* __restrict__ rd,
    const int* __restrict__ ei0, const int* __restrict__ ei1,
    int* __restrict__ hist,
    int Mrows, int nblkPad, int E_)
{
    const int tid = threadIdx.x;

    // ---- trailing blocks: edge histogram ----
    if ((int)blockIdx.x >= nblkPad) {
        int e = ((int)blockIdx.x - nblkPad) * 256 + tid;
        if (e < E_) {
            atomicAdd(&hist[ei0[E_ + e]], 1);
            atomicAdd(&hist[Mrows + ei1[E_ + e]], 1);
        }
        return;
    }

    int hw = blockIdx.x;
    int cpx = nblkPad >> 3;                // bijective chunked XCD swizzle
    int orig = (hw & 7) * cpx + (hw >> 3);
    int rt = orig >> 1;
    if (rt * 128 >= Mrows) return;         // pad blocks
    const int bn = (orig & 1) * 128;
    const int bm = rt * 128;

    const int lane = tid & 63, wv = tid >> 6;
    const int wr = wv >> 1, wc = wv & 1;

    f32x4 accL[4][4], accR[4][4];
#pragma unroll
    for (int m = 0; m < 4; m++)
#pragma unroll
        for (int n = 0; n < 4; n++) { accL[m][n] = (f32x4)0.f; accR[m][n] = (f32x4)0.f; }

    // per-wave fixed row/col bases
    int rowg[4];
#pragma unroll
    for (int m = 0; m < 4; m++) {
        int r = bm + wr * 64 + m * 16 + (lane & 15);
        rowg[m] = (r < Mrows) ? r : (Mrows - 1);
    }
    const int koff = (lane >> 4) * 8;      // k-slice within frag (8 elems)
    const unsigned short* bbase[4];
#pragma unroll
    for (int n = 0; n < 4; n++) {
        int col = bn + wc * 64 + n * 16 + (lane & 15);
        bbase[n] = Wb + (size_t)col * 256 + koff;
    }

#pragma unroll
    for (int t = 0; t < 8; t++) {
        const int k0 = t * 32;
        short8 bfrL[4], bfrR[4], afr[4];
#pragma unroll
        for (int n = 0; n < 4; n++) {
            bfrL[n] = *(const short8*)(bbase[n] + k0);
            bfrR[n] = *(const short8*)(bbase[n] + 65536 + k0);
        }
#pragma unroll
        for (int m = 0; m < 4; m++) {
            const float* ap = x + (size_t)rowg[m] * 256 + k0 + koff;
            float4 f0 = *(const float4*)ap;
            float4 f1 = *(const float4*)(ap + 4);
            union { short8 v; __hip_bfloat162 b2[4]; } u;
            u.b2[0] = __float22bfloat162_rn(make_float2(f0.x, f0.y));
            u.b2[1] = __float22bfloat162_rn(make_float2(f0.z, f0.w));
            u.b2[2] = __float22bfloat162_rn(make_float2(f1.x, f1.y));
            u.b2[3] = __float22bfloat162_rn(make_float2(f1.z, f1.w));
            afr[m] = u.v;
        }
#pragma unroll
        for (int m = 0; m < 4; m++)
#pragma unroll
            for (int n = 0; n < 4; n++) {
                accL[m][n] = __builtin_amdgcn_mfma_f32_16x16x32_bf16(
                    afr[m], bfrL[n], accL[m][n], 0, 0, 0);
                accR[m][n] = __builtin_amdgcn_mfma_f32_16x16x32_bf16(
                    afr[m], bfrR[n], accR[m][n], 0, 0, 0);
            }
    }

    // ---- fused epilogue: both outputs + all per-node logit partials ----
    const int NH = Mrows * H_;
    const int h = (bn >> 6) + wc;          // this wave's head
    float bvl[4], bvr[4], w0[4], w1[4], w2[4], u0[4];
    int gcol[4];
#pragma unroll
    for (int n = 0; n < 4; n++) {
        int c = n * 16 + (lane & 15);
        gcol[n] = bn + wc * 64 + c;
        bvl[n] = b_l[gcol[n]];
        bvr[n] = b_r[gcol[n]];
        w0[n] = attn[(0 * H_ + h) * 128 + 64 + c];
        w1[n] = attn[(1 * H_ + h) * 128 + 64 + c];
        w2[n] = rel_r[h * C_ + c];
        u0[n] = rel_l[h * C_ + c];
    }
#pragma unroll
    for (int m = 0; m < 4; m++) {
#pragma unroll
        for (int q = 0; q < 4; q++) {
            int grow = bm + wr * 64 + m * 16 + (lane >> 4) * 4 + q;
            bool ok = grow < Mrows;
            float p0 = 0.f, p1 = 0.f, p2 = 0.f, q0 = 0.f, q1 = 0.f;
#pragma unroll
            for (int n = 0; n < 4; n++) {
                float vl = accL[m][n][q] + bvl[n];
                float vr = accR[m][n][q] + bvr[n];
                if (ok) {
                    lout[(size_t)grow * 256 + gcol[n]] = f2b(vl);
                    if (RB16) ((unsigned short*)rout)[(size_t)grow * 256 + gcol[n]] = f2b(vr);
                    else      ((float*)rout)[(size_t)grow * 256 + gcol[n]] = vr;
                }
                float lr = lrelu(vl);
                p0 = fmaf(lr, w0[n], p0);
                p1 = fmaf(lr, w1[n], p1);
                p2 = fmaf(vl, w2[n], p2);
                q0 = fmaf(vr, u0[n], q0);
                q1 = fmaf(vr, w2[n], q1);
            }
#pragma unroll
            for (int off = 1; off < 16; off <<= 1) {
                p0 += __shfl_xor(p0, off);
                p1 += __shfl_xor(p1, off);
                p2 += __shfl_xor(p2, off);
                q0 += __shfl_xor(q0, off);
                q1 += __shfl_xor(q1, off);
            }
            if (ok && (lane & 15) == 0) {
                int nh = grow * H_ + h;
                float e0 = __expf(p0), e1 = __expf(p1);
                ej2[nh]      = make_float2(e0, e0 * p2);
                ej2[NH + nh] = make_float2(e1, e1 * p2);
                al[nh] = q0;
                rd[nh] = q1;
            }
        }
    }
}

// ---------- CSR build: 2-kernel exclusive scan (block sums folded downstream) ----------
__global__ __launch_bounds__(256) void scan_a(
    const int* __restrict__ hist, int* __restrict__ segoff,
    int* __restrict__ bsum, int Nn)
{
    int m = blockIdx.y;
    int gid = blockIdx.x * 256 + threadIdx.x;
    int lane = threadIdx.x & 63, wid = threadIdx.x >> 6;
    int v = (gid < Nn) ? hist[m * Nn + gid] : 0;
    int incl = v;
#pragma unroll
    for (int off = 1; off < 64; off <<= 1) {
        int u = __shfl_up(incl, off);
        if (lane >= off) incl += u;
    }
    __shared__ int ws[4], wo[4];
    if (lane == 63) ws[wid] = incl;
    __syncthreads();
    if (threadIdx.x == 0) {
        int run = 0;
#pragma unroll
        for (int i = 0; i < 4; i++) { wo[i] = run; run += ws[i]; }
        bsum[m * 512 + blockIdx.x] = run;
    }
    __syncthreads();
    if (gid < Nn) segoff[m * Nn + gid] = incl - v + wo[wid];
}

__global__ __launch_bounds__(512) void scan_b(int* __restrict__ bsum, int nb)
{
    int m = blockIdx.x;
    int* b = bsum + m * 512;
    int tid = threadIdx.x, lane = tid & 63, wid = tid >> 6;
    int v = (tid < nb) ? b[tid] : 0;
    int incl = v;
#pragma unroll
    for (int off = 1; off < 64; off <<= 1) {
        int u = __shfl_up(incl, off);
        if (lane >= off) incl += u;
    }
    __shared__ int ws[8], wo[8];
    if (lane == 63) ws[wid] = incl;
    __syncthreads();
    if (tid == 0) {
        int run = 0;
#pragma unroll
        for (int i = 0; i < 8; i++) { wo[i] = run; run += ws[i]; }
    }
    __syncthreads();
    if (tid < nb) b[tid] = incl - v + wo[wid];
}

// ---------- CSR build: scatter (adds bsum inline) ----------
__global__ __launch_bounds__(256) void edge_scatter(
    const int* __restrict__ ei0, const int* __restrict__ ei1,
    const int* __restrict__ segoff, const int* __restrict__ bsum,
    int* __restrict__ cursor, int* __restrict__ srcs, int E_, int Nn)
{
    int e = blockIdx.x * 256 + threadIdx.x;
    if (e >= E_) return;
    int t0 = ei0[E_ + e];
    int p0 = segoff[t0] + bsum[t0 >> 8] + atomicAdd(&cursor[t0], 1);
    srcs[p0] = ei0[e];
    int t1 = ei1[E_ + e];
    int p1 = segoff[Nn + t1] + bsum[512 + (t1 >> 8)] + atomicAdd(&cursor[Nn + t1], 1);
    srcs[E_ + p1] = ei1[e];
}

// ---------- single-pass aggregation: wave per target, dual accumulators ----------
template <bool RB16>
__global__ __launch_bounds__(256) void aggregate(
    const int* __restrict__ hist, const int* __restrict__ segoff,
    const int* __restrict__ bsum,
    const int* __restrict__ srcs, const float2* __restrict__ ej2,
    const float* __restrict__ al, const float* __restrict__ rd,
    const void* __restrict__ rv, const unsigned short* __restrict__ l,
    float* __restrict__ out, int Nn, int E_)
{
    int lane = threadIdx.x & 63;
    int t = blockIdx.x * 4 + (threadIdx.x >> 6);
    if (t >= Nn) return;
    int h = lane >> 4;
    int NH = Nn * H_;
    int nh = t * H_ + h;

    // issue these early: consumed only after the edge loops
    float4 rrow;
    if (RB16) {
        ushort4 ru = ((const ushort4*)rv)[(size_t)t * 64 + lane];
        rrow = make_float4(b2f(ru.x), b2f(ru.y), b2f(ru.z), b2f(ru.w));
    } else {
        rrow = ((const float4*)rv)[(size_t)t * 64 + lane];
    }
    float a = al[nh];
    float rdv = rd[nh];

    float4 accm[2];
    float denm[2], pnm[2];
#pragma unroll
    for (int m = 0; m < 2; m++) {
        const int* sp = srcs + (size_t)m * E_;
        const float2* ep = ej2 + (size_t)m * NH;
        int beg = segoff[m * Nn + t] + bsum[m * 512 + (t >> 8)];
        int deg = hist[m * Nn + t];

        float4 aA = make_float4(0.f, 0.f, 0.f, 0.f);
        float4 aB = make_float4(0.f, 0.f, 0.f, 0.f);
        float dA = 0.f, dB = 0.f, pA = 0.f, pB = 0.f;
        int j = 0;
#pragma unroll 2
        for (; j + 1 < deg; j += 2) {
            int s0 = sp[beg + j];
            int s1 = sp[beg + j + 1];
            float2 v0 = ep[(size_t)s0 * H_ + h];
            float2 v1 = ep[(size_t)s1 * H_ + h];
            ushort4 l0 = *(const ushort4*)&l[(size_t)s0 * D_ + lane * 4];
            ushort4 l1 = *(const ushort4*)&l[(size_t)s1 * D_ + lane * 4];
            dA += v0.x; pA += v0.y;
            dB += v1.x; pB += v1.y;
            aA.x = fmaf(b2f(l0.x), v0.x, aA.x);
            aA.y = fmaf(b2f(l0.y), v0.x, aA.y);
            aA.z = fmaf(b2f(l0.z), v0.x, aA.z);
            aA.w = fmaf(b2f(l0.w), v0.x, aA.w);
            aB.x = fmaf(b2f(l1.x), v1.x, aB.x);
            aB.y = fmaf(b2f(l1.y), v1.x, aB.y);
            aB.z = fmaf(b2f(l1.z), v1.x, aB.z);
            aB.w = fmaf(b2f(l1.w), v1.x, aB.w);
        }
        if (j < deg) {
            int s0 = sp[beg + j];
            float2 v0 = ep[(size_t)s0 * H_ + h];
            ushort4 l0 = *(const ushort4*)&l[(size_t)s0 * D_ + lane * 4];
            dA += v0.x; pA += v0.y;
            aA.x = fmaf(b2f(l0.x), v0.x, aA.x);
            aA.y = fmaf(b2f(l0.y), v0.x, aA.y);
            aA.z = fmaf(b2f(l0.z), v0.x, aA.z);
            aA.w = fmaf(b2f(l0.w), v0.x, aA.w);
        }
        accm[m] = make_float4(aA.x + aB.x, aA.y + aB.y, aA.z + aB.z, aA.w + aB.w);
        denm[m] = dA + dB;
        pnm[m] = pA + pB;
    }

    float b0 = lrelu(a + pnm[0] / (denm[0] + 1e-16f));
    float b1 = lrelu(a + pnm[1] / (denm[1] + 1e-16f));
    float b2 = lrelu(a + rdv);
    float mm = fmaxf(b0, fmaxf(b1, b2));
    float e0 = __expf(b0 - mm), e1 = __expf(b1 - mm), e2 = __expf(b2 - mm);
    float inv = 1.f / (e0 + e1 + e2);
    float wm0 = e0 * inv / (denm[0] + 1e-16f);
    float wm1 = e1 * inv / (denm[1] + 1e-16f);
    float b2v = e2 * inv;

    float4 o;
    o.x = fmaxf(fmaf(wm0, accm[0].x, fmaf(wm1, accm[1].x, b2v * rrow.x)), 0.f);
    o.y = fmaxf(fmaf(wm0, accm[0].y, fmaf(wm1, accm[1].y, b2v * rrow.y)), 0.f);
    o.z = fmaxf(fmaf(wm0, accm[0].z, fmaf(wm1, accm[1].z, b2v * rrow.z)), 0.f);
    o.w = fmaxf(fmaf(wm0, accm[0].w, fmaf(wm1, accm[1].w, b2v * rrow.w)), 0.f);
    *(float4*)&out[(size_t)t * D_ + lane * 4] = o;
}

extern "C" void kernel_launch(void* const* d_in, const int* in_sizes, int n_in,
                              void* d_out, int out_size, void* d_ws, size_t ws_size,
                              hipStream_t stream) {
    const float* x     = (const float*)d_in[0];
    const int*   ei0   = (const int*)d_in[1];
    const int*   ei1   = (const int*)d_in[2];
    const float* W_l   = (const float*)d_in[3];
    const float* b_l   = (const float*)d_in[4];
    const float* W_r   = (const float*)d_in[5];
    const float* b_r   = (const float*)d_in[6];
    const float* attn  = (const float*)d_in[7];
    const float* rel_l = (const float*)d_in[8];
    const float* rel_r = (const float*)d_in[9];
    float* out = (float*)d_out;

    const int Nn = in_sizes[0] / D_;        // 100000
    const int E_ = in_sizes[1] / 2;         // 800000
    const size_t ND = (size_t)Nn * D_;
    const int NH = Nn * H_;

    // ---- workspace layout (~70 MB base; +51 MB rb — proven to fit) ----
    char* base = (char*)d_ws;
    unsigned short* l = (unsigned short*)base;      size_t off = ND * 2;
    float2* ej2  = (float2*)(base + off); off += (size_t)2 * NH * 8;  // [M][N][H]
    float* al    = (float*)(base + off);  off += (size_t)NH * 4;
    float* rd    = (float*)(base + off);  off += (size_t)NH * 4;
    int* hist    = (int*)(base + off);    off += (size_t)2 * Nn * 4;  // [M][Nn]
    int* cursor  = (int*)(base + off);    off += (size_t)2 * Nn * 4;
    int* segoff  = (int*)(base + off);    off += (size_t)2 * Nn * 4;
    int* bsum    = (int*)(base + off);    off += (size_t)1024 * 4;
    int* srcs    = (int*)(base + off);    off += (size_t)2 * E_ * 4;  // [M][E]
    unsigned short* Wb = (unsigned short*)(base + off); off += (size_t)2 * 65536 * 2;
    unsigned short* rb = (unsigned short*)(base + off);
    const bool rb16 = (ws_size >= off + ND * 2);    // proven true
    void* r_any = rb16 ? (void*)rb : (void*)out;

    // zero hist + cursor (contiguous)
    hipMemsetAsync(hist, 0, (size_t)4 * Nn * 4, stream);

    convert_w<<<128, 256, 0, stream>>>(W_l, W_r, Wb);

    int rowTiles = (Nn + 127) / 128;       // 782
    int nblk = 2 * rowTiles;               // 1564 (merged sel)
    int nblkPad = (nblk + 7) & ~7;         // 1568, divisible by 8
    int eb = (E_ + 255) / 256;             // 3125 hist blocks trail
    if (rb16)
        gemm_hist<true ><<<nblkPad + eb, 256, 0, stream>>>(
            x, Wb, b_l, b_r, attn, rel_l, rel_r, l, r_any, ej2, al, rd,
            ei0, ei1, hist, Nn, nblkPad, E_);
    else
        gemm_hist<false><<<nblkPad + eb, 256, 0, stream>>>(
            x, Wb, b_l, b_r, attn, rel_l, rel_r, l, r_any, ej2, al, rd,
            ei0, ei1, hist, Nn, nblkPad, E_);

    int nb = (Nn + 255) / 256;   // 391
    scan_a<<<dim3(nb, 2), 256, 0, stream>>>(hist, segoff, bsum, Nn);
    scan_b<<<2, 512, 0, stream>>>(bsum, nb);
    edge_scatter<<<eb, 256, 0, stream>>>(ei0, ei1, segoff, bsum, cursor, srcs, E_, Nn);

    if (rb16)
        aggregate<true ><<<(Nn + 3) / 4, 256, 0, stream>>>(
            hist, segoff, bsum, srcs, ej2, al, rd, r_any, l, out, Nn, E_);
    else
        aggregate<false><<<(Nn + 3) / 4, 256, 0, stream>>>(
            hist, segoff, bsum, srcs, ej2, al, rd, r_any, l, out, Nn, E_);
}

// Round 19
// 395.513 us; speedup vs baseline: 1.1551x; 1.1551x over previous
//
#include <hip/hip_runtime.h>
#include <hip/hip_bf16.h>
#include <math.h>

#define D_ 256
#define H_ 4
#define C_ 64

typedef __attribute__((ext_vector_type(8))) short short8;
typedef __attribute__((ext_vector_type(4))) float f32x4;

// ---------- helpers ----------
__device__ inline float lrelu(float v) { return v >= 0.f ? v : 0.2f * v; }

// bf16 bit helpers
__device__ inline unsigned short f2b(float f) {
    unsigned u = __float_as_uint(f);
    u = (u + 0x7FFFu + ((u >> 16) & 1u)) >> 16;   // round-to-nearest-even
    return (unsigned short)u;
}
__device__ inline float b2f(unsigned short u) {
    return __uint_as_float(((unsigned)u) << 16);
}

#define GLDS(src, dst) __builtin_amdgcn_global_load_lds(                      \
    (const __attribute__((address_space(1))) void*)(src),                     \
    (__attribute__((address_space(3))) void*)(dst), 16, 0, 0)

// ---------- W -> bf16 ----------
__global__ __launch_bounds__(256) void convert_w(
    const float* __restrict__ Wl, const float* __restrict__ Wr,
    unsigned short* __restrict__ Wb)
{
    int i4 = blockIdx.x * 256 + threadIdx.x;          // 0..32767 float4s
    float4 v = (i4 < 16384) ? ((const float4*)Wl)[i4]
                            : ((const float4*)Wr)[i4 - 16384];
    ushort4 u;
    u.x = f2b(v.x); u.y = f2b(v.y); u.z = f2b(v.z); u.w = f2b(v.w);
    ((ushort4*)Wb)[i4] = u;
}

// ---------- staging ----------
// LDS staging is load-coalescing + fragment-transpose (r18 removed it: each
// direct fragment load touched 16 cache lines -> 217us. Keep GLDS+LDS.)
__device__ __forceinline__ void stage_a(const float* __restrict__ x, float* dst,
                                        int bm, int k0, int wv, int lane, int Mrows)
{
#pragma unroll
    for (int p = 0; p < 4; p++) {
        int ci = (p * 4 + wv) * 64 + lane;            // chunk 0..1023
        int row = ci >> 3, cc = ci & 7;
        int gr = bm + row; if (gr >= Mrows) gr = Mrows - 1;
        const float* src = x + (size_t)gr * 256 + k0 + ((cc ^ (row & 7)) << 2);
        GLDS(src, (char*)dst + (size_t)(p * 4 + wv) * 1024);
    }
}
// stage BOTH W_l and W_r tiles (selb-major chunk layout matches Bs[2][128*32])
__device__ __forceinline__ void stage_b2(const unsigned short* __restrict__ Wb,
                                         unsigned short* dst, int bn, int k0,
                                         int wv, int lane)
{
#pragma unroll
    for (int p = 0; p < 4; p++) {
        int ci = (p * 4 + wv) * 64 + lane;            // chunk 0..1023
        int selb = ci >> 9, cj = ci & 511;
        int col = cj >> 2, cc = cj & 3;
        const unsigned short* src = Wb + (size_t)selb * 65536 +
                                    (size_t)(bn + col) * 256 + k0 +
                                    ((cc ^ ((col >> 1) & 3)) << 3);
        GLDS(src, (char*)dst + (size_t)(p * 4 + wv) * 1024);
    }
}

// ---------- merged MFMA GEMM: one block computes l AND r for its tile ----------
// A staged once per tile (was twice); 32 MFMA per barrier pair (was 16) ->
// halves the vmcnt(0)+barrier drains per output element, the structural stall.
template <bool RB16>
__global__ __launch_bounds__(256, 2) void gemm_hist(
    const float* __restrict__ x, const unsigned short* __restrict__ Wb,
    const float* __restrict__ b_l, const float* __restrict__ b_r,
    const float* __restrict__ attn, const float* __restrict__ rel_l,
    const float* __restrict__ rel_r,
    unsigned short* __restrict__ lout, void* __restrict__ rout,
    float2* __restrict__ ej2, float* __restrict__ al, float* __restrict__ rd,
    const int* __restrict__ ei0, const int* __restrict__ ei1,
    int* __restrict__ hist,
    int Mrows, int nblkPad, int E_)
{
    const int tid = threadIdx.x;

    // ---- trailing blocks: edge histogram ----
    if ((int)blockIdx.x >= nblkPad) {
        int e = ((int)blockIdx.x - nblkPad) * 256 + tid;
        if (e < E_) {
            atomicAdd(&hist[ei0[E_ + e]], 1);
            atomicAdd(&hist[Mrows + ei1[E_ + e]], 1);
        }
        return;
    }

    int hw = blockIdx.x;
    int cpx = nblkPad >> 3;                // bijective chunked XCD swizzle
    int orig = (hw & 7) * cpx + (hw >> 3);
    int rt = orig >> 1;
    if (rt * 128 >= Mrows) return;         // pad blocks
    const int bn = (orig & 1) * 128;
    const int bm = rt * 128;

    __shared__ float As[2][128 * 32];              // 32 KB
    __shared__ unsigned short Bs[2][2][128 * 32];  // 32 KB (both W tiles)
    const int lane = tid & 63, wv = tid >> 6;
    const int wr = wv >> 1, wc = wv & 1;

    f32x4 accL[4][4], accR[4][4];
#pragma unroll
    for (int m = 0; m < 4; m++)
#pragma unroll
        for (int n = 0; n < 4; n++) { accL[m][n] = (f32x4)0.f; accR[m][n] = (f32x4)0.f; }

    stage_a(x, As[0], bm, 0, wv, lane, Mrows);
    stage_b2(Wb, &Bs[0][0][0], bn, 0, wv, lane);
    __syncthreads();

    int cur = 0;
#pragma unroll
    for (int t = 0; t < 8; t++) {
        if (t < 7) {
            stage_a(x, As[cur ^ 1], bm, (t + 1) * 32, wv, lane, Mrows);
            stage_b2(Wb, &Bs[cur ^ 1][0][0], bn, (t + 1) * 32, wv, lane);
        }
        short8 bfrL[4], bfrR[4], afr[4];
#pragma unroll
        for (int n = 0; n < 4; n++) {
            int col = wc * 64 + n * 16 + (lane & 15);
            int sc = (lane >> 4) ^ ((col >> 1) & 3);
            bfrL[n] = *(const short8*)&Bs[cur][0][col * 32 + sc * 8];
            bfrR[n] = *(const short8*)&Bs[cur][1][col * 32 + sc * 8];
        }
#pragma unroll
        for (int m = 0; m < 4; m++) {
            int row = wr * 64 + m * 16 + (lane & 15);
            int c0 = (lane >> 4) * 2;
            const float* ap = &As[cur][row * 32];
            float4 f0 = *(const float4*)&ap[(c0 ^ (row & 7)) << 2];
            float4 f1 = *(const float4*)&ap[((c0 + 1) ^ (row & 7)) << 2];
            union { short8 v; __hip_bfloat162 b2[4]; } u;
            u.b2[0] = __float22bfloat162_rn(make_float2(f0.x, f0.y));
            u.b2[1] = __float22bfloat162_rn(make_float2(f0.z, f0.w));
            u.b2[2] = __float22bfloat162_rn(make_float2(f1.x, f1.y));
            u.b2[3] = __float22bfloat162_rn(make_float2(f1.z, f1.w));
            afr[m] = u.v;
        }
#pragma unroll
        for (int m = 0; m < 4; m++)
#pragma unroll
            for (int n = 0; n < 4; n++) {
                accL[m][n] = __builtin_amdgcn_mfma_f32_16x16x32_bf16(
                    afr[m], bfrL[n], accL[m][n], 0, 0, 0);
                accR[m][n] = __builtin_amdgcn_mfma_f32_16x16x32_bf16(
                    afr[m], bfrR[n], accR[m][n], 0, 0, 0);
            }
        __syncthreads();
        cur ^= 1;
    }

    // ---- fused epilogue: both outputs + all per-node logit partials ----
    const int NH = Mrows * H_;
    const int h = (bn >> 6) + wc;          // this wave's head
    float bvl[4], bvr[4], w0[4], w1[4], w2[4], u0[4];
    int gcol[4];
#pragma unroll
    for (int n = 0; n < 4; n++) {
        int c = n * 16 + (lane & 15);
        gcol[n] = bn + wc * 64 + c;
        bvl[n] = b_l[gcol[n]];
        bvr[n] = b_r[gcol[n]];
        w0[n] = attn[(0 * H_ + h) * 128 + 64 + c];
        w1[n] = attn[(1 * H_ + h) * 128 + 64 + c];
        w2[n] = rel_r[h * C_ + c];
        u0[n] = rel_l[h * C_ + c];
    }
#pragma unroll
    for (int m = 0; m < 4; m++) {
#pragma unroll
        for (int q = 0; q < 4; q++) {
            int grow = bm + wr * 64 + m * 16 + (lane >> 4) * 4 + q;
            bool ok = grow < Mrows;
            float p0 = 0.f, p1 = 0.f, p2 = 0.f, q0 = 0.f, q1 = 0.f;
#pragma unroll
            for (int n = 0; n < 4; n++) {
                float vl = accL[m][n][q] + bvl[n];
                float vr = accR[m][n][q] + bvr[n];
                if (ok) {
                    lout[(size_t)grow * 256 + gcol[n]] = f2b(vl);
                    if (RB16) ((unsigned short*)rout)[(size_t)grow * 256 + gcol[n]] = f2b(vr);
                    else      ((float*)rout)[(size_t)grow * 256 + gcol[n]] = vr;
                }
                float lr = lrelu(vl);
                p0 = fmaf(lr, w0[n], p0);
                p1 = fmaf(lr, w1[n], p1);
                p2 = fmaf(vl, w2[n], p2);
                q0 = fmaf(vr, u0[n], q0);
                q1 = fmaf(vr, w2[n], q1);
            }
#pragma unroll
            for (int off = 1; off < 16; off <<= 1) {
                p0 += __shfl_xor(p0, off);
                p1 += __shfl_xor(p1, off);
                p2 += __shfl_xor(p2, off);
                q0 += __shfl_xor(q0, off);
                q1 += __shfl_xor(q1, off);
            }
            if (ok && (lane & 15) == 0) {
                int nh = grow * H_ + h;
                float e0 = __expf(p0), e1 = __expf(p1);
                ej2[nh]      = make_float2(e0, e0 * p2);
                ej2[NH + nh] = make_float2(e1, e1 * p2);
                al[nh] = q0;
                rd[nh] = q1;
            }
        }
    }
}

// ---------- CSR build: 2-kernel exclusive scan (block sums folded downstream) ----------
__global__ __launch_bounds__(256) void scan_a(
    const int* __restrict__ hist, int* __restrict__ segoff,
    int* __restrict__ bsum, int Nn)
{
    int m = blockIdx.y;
    int gid = blockIdx.x * 256 + threadIdx.x;
    int lane = threadIdx.x & 63, wid = threadIdx.x >> 6;
    int v = (gid < Nn) ? hist[m * Nn + gid] : 0;
    int incl = v;
#pragma unroll
    for (int off = 1; off < 64; off <<= 1) {
        int u = __shfl_up(incl, off);
        if (lane >= off) incl += u;
    }
    __shared__ int ws[4], wo[4];
    if (lane == 63) ws[wid] = incl;
    __syncthreads();
    if (threadIdx.x == 0) {
        int run = 0;
#pragma unroll
        for (int i = 0; i < 4; i++) { wo[i] = run; run += ws[i]; }
        bsum[m * 512 + blockIdx.x] = run;
    }
    __syncthreads();
    if (gid < Nn) segoff[m * Nn + gid] = incl - v + wo[wid];
}

__global__ __launch_bounds__(512) void scan_b(int* __restrict__ bsum, int nb)
{
    int m = blockIdx.x;
    int* b = bsum + m * 512;
    int tid = threadIdx.x, lane = tid & 63, wid = tid >> 6;
    int v = (tid < nb) ? b[tid] : 0;
    int incl = v;
#pragma unroll
    for (int off = 1; off < 64; off <<= 1) {
        int u = __shfl_up(incl, off);
        if (lane >= off) incl += u;
    }
    __shared__ int ws[8], wo[8];
    if (lane == 63) ws[wid] = incl;
    __syncthreads();
    if (tid == 0) {
        int run = 0;
#pragma unroll
        for (int i = 0; i < 8; i++) { wo[i] = run; run += ws[i]; }
    }
    __syncthreads();
    if (tid < nb) b[tid] = incl - v + wo[wid];
}

// ---------- CSR build: scatter (adds bsum inline) ----------
__global__ __launch_bounds__(256) void edge_scatter(
    const int* __restrict__ ei0, const int* __restrict__ ei1,
    const int* __restrict__ segoff, const int* __restrict__ bsum,
    int* __restrict__ cursor, int* __restrict__ srcs, int E_, int Nn)
{
    int e = blockIdx.x * 256 + threadIdx.x;
    if (e >= E_) return;
    int t0 = ei0[E_ + e];
    int p0 = segoff[t0] + bsum[t0 >> 8] + atomicAdd(&cursor[t0], 1);
    srcs[p0] = ei0[e];
    int t1 = ei1[E_ + e];
    int p1 = segoff[Nn + t1] + bsum[512 + (t1 >> 8)] + atomicAdd(&cursor[Nn + t1], 1);
    srcs[E_ + p1] = ei1[e];
}

// ---------- single-pass aggregation: wave per target, dual accumulators ----------
template <bool RB16>
__global__ __launch_bounds__(256) void aggregate(
    const int* __restrict__ hist, const int* __restrict__ segoff,
    const int* __restrict__ bsum,
    const int* __restrict__ srcs, const float2* __restrict__ ej2,
    const float* __restrict__ al, const float* __restrict__ rd,
    const void* __restrict__ rv, const unsigned short* __restrict__ l,
    float* __restrict__ out, int Nn, int E_)
{
    int lane = threadIdx.x & 63;
    int t = blockIdx.x * 4 + (threadIdx.x >> 6);
    if (t >= Nn) return;
    int h = lane >> 4;
    int NH = Nn * H_;
    int nh = t * H_ + h;

    // issue these early: consumed only after the edge loops
    float4 rrow;
    if (RB16) {
        ushort4 ru = ((const ushort4*)rv)[(size_t)t * 64 + lane];
        rrow = make_float4(b2f(ru.x), b2f(ru.y), b2f(ru.z), b2f(ru.w));
    } else {
        rrow = ((const float4*)rv)[(size_t)t * 64 + lane];
    }
    float a = al[nh];
    float rdv = rd[nh];

    float4 accm[2];
    float denm[2], pnm[2];
#pragma unroll
    for (int m = 0; m < 2; m++) {
        const int* sp = srcs + (size_t)m * E_;
        const float2* ep = ej2 + (size_t)m * NH;
        int beg = segoff[m * Nn + t] + bsum[m * 512 + (t >> 8)];
        int deg = hist[m * Nn + t];

        float4 aA = make_float4(0.f, 0.f, 0.f, 0.f);
        float4 aB = make_float4(0.f, 0.f, 0.f, 0.f);
        float dA = 0.f, dB = 0.f, pA = 0.f, pB = 0.f;
        int j = 0;
#pragma unroll 2
        for (; j + 1 < deg; j += 2) {
            int s0 = sp[beg + j];
            int s1 = sp[beg + j + 1];
            float2 v0 = ep[(size_t)s0 * H_ + h];
            float2 v1 = ep[(size_t)s1 * H_ + h];
            ushort4 l0 = *(const ushort4*)&l[(size_t)s0 * D_ + lane * 4];
            ushort4 l1 = *(const ushort4*)&l[(size_t)s1 * D_ + lane * 4];
            dA += v0.x; pA += v0.y;
            dB += v1.x; pB += v1.y;
            aA.x = fmaf(b2f(l0.x), v0.x, aA.x);
            aA.y = fmaf(b2f(l0.y), v0.x, aA.y);
            aA.z = fmaf(b2f(l0.z), v0.x, aA.z);
            aA.w = fmaf(b2f(l0.w), v0.x, aA.w);
            aB.x = fmaf(b2f(l1.x), v1.x, aB.x);
            aB.y = fmaf(b2f(l1.y), v1.x, aB.y);
            aB.z = fmaf(b2f(l1.z), v1.x, aB.z);
            aB.w = fmaf(b2f(l1.w), v1.x, aB.w);
        }
        if (j < deg) {
            int s0 = sp[beg + j];
            float2 v0 = ep[(size_t)s0 * H_ + h];
            ushort4 l0 = *(const ushort4*)&l[(size_t)s0 * D_ + lane * 4];
            dA += v0.x; pA += v0.y;
            aA.x = fmaf(b2f(l0.x), v0.x, aA.x);
            aA.y = fmaf(b2f(l0.y), v0.x, aA.y);
            aA.z = fmaf(b2f(l0.z), v0.x, aA.z);
            aA.w = fmaf(b2f(l0.w), v0.x, aA.w);
        }
        accm[m] = make_float4(aA.x + aB.x, aA.y + aB.y, aA.z + aB.z, aA.w + aB.w);
        denm[m] = dA + dB;
        pnm[m] = pA + pB;
    }

    float b0 = lrelu(a + pnm[0] / (denm[0] + 1e-16f));
    float b1 = lrelu(a + pnm[1] / (denm[1] + 1e-16f));
    float b2 = lrelu(a + rdv);
    float mm = fmaxf(b0, fmaxf(b1, b2));
    float e0 = __expf(b0 - mm), e1 = __expf(b1 - mm), e2 = __expf(b2 - mm);
    float inv = 1.f / (e0 + e1 + e2);
    float wm0 = e0 * inv / (denm[0] + 1e-16f);
    float wm1 = e1 * inv / (denm[1] + 1e-16f);
    float b2v = e2 * inv;

    float4 o;
    o.x = fmaxf(fmaf(wm0, accm[0].x, fmaf(wm1, accm[1].x, b2v * rrow.x)), 0.f);
    o.y = fmaxf(fmaf(wm0, accm[0].y, fmaf(wm1, accm[1].y, b2v * rrow.y)), 0.f);
    o.z = fmaxf(fmaf(wm0, accm[0].z, fmaf(wm1, accm[1].z, b2v * rrow.z)), 0.f);
    o.w = fmaxf(fmaf(wm0, accm[0].w, fmaf(wm1, accm[1].w, b2v * rrow.w)), 0.f);
    *(float4*)&out[(size_t)t * D_ + lane * 4] = o;
}

extern "C" void kernel_launch(void* const* d_in, const int* in_sizes, int n_in,
                              void* d_out, int out_size, void* d_ws, size_t ws_size,
                              hipStream_t stream) {
    const float* x     = (const float*)d_in[0];
    const int*   ei0   = (const int*)d_in[1];
    const int*   ei1   = (const int*)d_in[2];
    const float* W_l   = (const float*)d_in[3];
    const float* b_l   = (const float*)d_in[4];
    const float* W_r   = (const float*)d_in[5];
    const float* b_r   = (const float*)d_in[6];
    const float* attn  = (const float*)d_in[7];
    const float* rel_l = (const float*)d_in[8];
    const float* rel_r = (const float*)d_in[9];
    float* out = (float*)d_out;

    const int Nn = in_sizes[0] / D_;        // 100000
    const int E_ = in_sizes[1] / 2;         // 800000
    const size_t ND = (size_t)Nn * D_;
    const int NH = Nn * H_;

    // ---- workspace layout (~70 MB base; +51 MB rb — proven to fit) ----
    char* base = (char*)d_ws;
    unsigned short* l = (unsigned short*)base;      size_t off = ND * 2;
    float2* ej2  = (float2*)(base + off); off += (size_t)2 * NH * 8;  // [M][N][H]
    float* al    = (float*)(base + off);  off += (size_t)NH * 4;
    float* rd    = (float*)(base + off);  off += (size_t)NH * 4;
    int* hist    = (int*)(base + off);    off += (size_t)2 * Nn * 4;  // [M][Nn]
    int* cursor  = (int*)(base + off);    off += (size_t)2 * Nn * 4;
    int* segoff  = (int*)(base + off);    off += (size_t)2 * Nn * 4;
    int* bsum    = (int*)(base + off);    off += (size_t)1024 * 4;
    int* srcs    = (int*)(base + off);    off += (size_t)2 * E_ * 4;  // [M][E]
    unsigned short* Wb = (unsigned short*)(base + off); off += (size_t)2 * 65536 * 2;
    unsigned short* rb = (unsigned short*)(base + off);
    const bool rb16 = (ws_size >= off + ND * 2);    // proven true
    void* r_any = rb16 ? (void*)rb : (void*)out;

    // zero hist + cursor (contiguous)
    hipMemsetAsync(hist, 0, (size_t)4 * Nn * 4, stream);

    convert_w<<<128, 256, 0, stream>>>(W_l, W_r, Wb);

    int rowTiles = (Nn + 127) / 128;       // 782
    int nblk = 2 * rowTiles;               // 1564 (merged sel)
    int nblkPad = (nblk + 7) & ~7;         // 1568, divisible by 8
    int eb = (E_ + 255) / 256;             // 3125 hist blocks trail
    if (rb16)
        gemm_hist<true ><<<nblkPad + eb, 256, 0, stream>>>(
            x, Wb, b_l, b_r, attn, rel_l, rel_r, l, r_any, ej2, al, rd,
            ei0, ei1, hist, Nn, nblkPad, E_);
    else
        gemm_hist<false><<<nblkPad + eb, 256, 0, stream>>>(
            x, Wb, b_l, b_r, attn, rel_l, rel_r, l, r_any, ej2, al, rd,
            ei0, ei1, hist, Nn, nblkPad, E_);

    int nb = (Nn + 255) / 256;   // 391
    scan_a<<<dim3(nb, 2), 256, 0, stream>>>(hist, segoff, bsum, Nn);
    scan_b<<<2, 512, 0, stream>>>(bsum, nb);
    edge_scatter<<<eb, 256, 0, stream>>>(ei0, ei1, segoff, bsum, cursor, srcs, E_, Nn);

    if (rb16)
        aggregate<true ><<<(Nn + 3) / 4, 256, 0, stream>>>(
            hist, segoff, bsum, srcs, ej2, al, rd, r_any, l, out, Nn, E_);
    else
        aggregate<false><<<(Nn + 3) / 4, 256, 0, stream>>>(
            hist, segoff, bsum, srcs, ej2, al, rd, r_any, l, out, Nn, E_);
}